// Round 7
// baseline (156.184 us; speedup 1.0000x reference)
//
#include <hip/hip_runtime.h>
#include <math.h>

// CapsuleLayer dynamic routing, fused. R7: 1024-thread workgroup.
// Lesson ledger: R2/R3/R6 — every waves_per_eu/launch_bounds attribute lands
// at the 64-VGPR default cap and spills pri[] (R6: WRITE_SIZE 38 MB).
// R5 — no attribute + LDS-limited occupancy -> allocator gives exactly
// demand (72 regs, zero spill). So: make the 128-reg budget STRUCTURAL:
// 1024 threads = 16 waves on one CU = >=4 waves/EU -> cap 128 by shape;
// LDS 86 KB -> exactly 1 block/CU. Spend the budget: pri shrinks to
// 5 float4/batch (MB=2 -> 40 regs) and Phase A runs a 1-tile-ahead W
// prefetch (wreg/wnxt, 64 regs in flight) -> 2x memory concurrency/wave.
// c-major blocks: 128 consecutive blocks share W[c] (589 KB) in L2.

#define NC 10
#define NR 1152
#define IC 8
#define OC 16
#define NITER 3
#define T 1024
#define MB 2

__device__ __forceinline__ float wave_sum(float v) {
#pragma unroll
    for (int m = 1; m <= 32; m <<= 1) v += __shfl_xor(v, m, 64);
    return v;
}
__device__ __forceinline__ float wave_max(float v) {
#pragma unroll
    for (int m = 1; m <= 32; m <<= 1) v = fmaxf(v, __shfl_xor(v, m, 64));
    return v;
}

__global__ __launch_bounds__(T) void caps_route(
    const float* __restrict__ x,   // [B, NR, IC]
    const float* __restrict__ W,   // [NC, NR, IC, OC]
    float* __restrict__ out)       // [B, NC, OC]
{
    // smem[0..18431]: Phase A = x[b0]||x[b1] (73728 B); Phase B overlay =
    // logit0[NR]||logit1[NR]. +red(512)+vout(32). Declared 21504 floats
    // (86016 B) to pin 1 block/CU (-> 4 waves/EU scheduler target).
    __shared__ float smem[21504];
    float* red  = smem + 18432;    // [2][16 waves][16 o]
    float* vout = smem + 18944;    // [2][16]

    const int t    = threadIdx.x;
    const int og   = t & 3;        // o-quad (o = og*4+j)
    const int rr   = t >> 2;       // 0..255
    const int lane = t & 63;
    const int wid  = t >> 6;       // 0..15
    const bool has4 = (rr < 128);  // p=4 tile ownership; wave-uniform (waves 0..7)

    const int c  = blockIdx.x >> 7;     // c-major
    const int b0 = (blockIdx.x & 127) * 2;

    // ---------------- stage x[b0],x[b1] into LDS ---------------------------
    float4* xs4 = (float4*)smem;        // 4608 float4
    const float4* __restrict__ xg = (const float4*)(x + (size_t)b0 * (NR * IC));
    for (int k = t; k < NR * 4; k += T) xs4[k] = xg[k];
    __syncthreads();

    // ---------------- Phase A: priors, r = rr+256p (p<4), 1024+rr (p=4) ----
    const float4* __restrict__ wb = (const float4*)(W + (size_t)c * (NR * IC * OC));
    const float4* xb0 = xs4;
    const float4* xb1 = xs4 + NR * 2;
    const int r4 = has4 ? (1024 + rr) : 1151;   // clamp: harmless in-range read

    float4 pri0[5], pri1[5];
    float4 wreg[8];
#pragma unroll
    for (int i = 0; i < 8; ++i) wreg[i] = wb[(size_t)rr * 32 + i * 4 + og];

#pragma unroll
    for (int p = 0; p < 5; ++p) {
        const int r = (p < 4) ? (rr + (p << 8)) : r4;
        float4 wnxt[8];
        if (p < 4) {                     // prefetch next tile's 8 W float4s
            const int rn = (p < 3) ? (rr + ((p + 1) << 8)) : r4;
#pragma unroll
            for (int i = 0; i < 8; ++i) wnxt[i] = wb[(size_t)rn * 32 + i * 4 + og];
        }
        float4 xa0 = xb0[2 * r], xc0 = xb0[2 * r + 1];
        float4 xa1 = xb1[2 * r], xc1 = xb1[2 * r + 1];
        float xv0[8] = {xa0.x, xa0.y, xa0.z, xa0.w, xc0.x, xc0.y, xc0.z, xc0.w};
        float xv1[8] = {xa1.x, xa1.y, xa1.z, xa1.w, xc1.x, xc1.y, xc1.z, xc1.w};
        float4 a0 = make_float4(0.f, 0.f, 0.f, 0.f);
        float4 a1 = make_float4(0.f, 0.f, 0.f, 0.f);
#pragma unroll
        for (int i = 0; i < 8; ++i) {
            float4 w = wreg[i];          // one load feeds both batches
            a0.x = fmaf(xv0[i], w.x, a0.x); a1.x = fmaf(xv1[i], w.x, a1.x);
            a0.y = fmaf(xv0[i], w.y, a0.y); a1.y = fmaf(xv1[i], w.y, a1.y);
            a0.z = fmaf(xv0[i], w.z, a0.z); a1.z = fmaf(xv1[i], w.z, a1.z);
            a0.w = fmaf(xv0[i], w.w, a0.w); a1.w = fmaf(xv1[i], w.w, a1.w);
        }
        pri0[p] = a0; pri1[p] = a1;      // p=4 garbage for !has4 — never read
        if (p < 4) {
#pragma unroll
            for (int i = 0; i < 8; ++i) wreg[i] = wnxt[i];
        }
    }
    float* logit0 = smem;                // overlay: x dead, logits live
    float* logit1 = smem + NR;

    // ---------------- Phase B: 3 routing iterations -------------------------
    for (int it = 0; it < NITER; ++it) {
        const bool uni = (it == 0);      // softmax of zeros = uniform
        float m0 = 0.f, m1 = 0.f, invd0 = 0.f, invd1 = 0.f;
        if (!uni) {
            // max: r=t (all), r=1024+t (t<128)
            float l0 = logit0[t], l1 = logit1[t];
            float lm0 = l0, lm1 = l1;
            if (t < 128) {
                lm0 = fmaxf(lm0, logit0[1024 + t]);
                lm1 = fmaxf(lm1, logit1[1024 + t]);
            }
            lm0 = wave_max(lm0); lm1 = wave_max(lm1);
            if (lane == 0) { red[wid] = lm0; red[16 + wid] = lm1; }
            __syncthreads();
            m0 = red[0]; m1 = red[16];
#pragma unroll
            for (int w = 1; w < 16; ++w) {
                m0 = fmaxf(m0, red[w]); m1 = fmaxf(m1, red[16 + w]);
            }
            float e0 = __expf(l0 - m0), e1 = __expf(l1 - m1);
            if (t < 128) {
                e0 += __expf(logit0[1024 + t] - m0);
                e1 += __expf(logit1[1024 + t] - m1);
            }
            e0 = wave_sum(e0); e1 = wave_sum(e1);
            __syncthreads();             // m reads done before red rewrite
            if (lane == 0) { red[wid] = e0; red[16 + wid] = e1; }
            __syncthreads();
            float d0 = red[0], d1 = red[16];
#pragma unroll
            for (int w = 1; w < 16; ++w) { d0 += red[w]; d1 += red[16 + w]; }
            invd0 = 1.f / d0; invd1 = 1.f / d1;
        }

        // s[o] partials, both batches
        float4 s0 = make_float4(0.f, 0.f, 0.f, 0.f);
        float4 s1 = make_float4(0.f, 0.f, 0.f, 0.f);
#pragma unroll
        for (int p = 0; p < 4; ++p) {
            float w0 = 1.0f, w1 = 1.0f;
            if (!uni) {
                const int r = rr + (p << 8);
                w0 = __expf(logit0[r] - m0);
                w1 = __expf(logit1[r] - m1);
            }
            s0.x = fmaf(w0, pri0[p].x, s0.x); s1.x = fmaf(w1, pri1[p].x, s1.x);
            s0.y = fmaf(w0, pri0[p].y, s0.y); s1.y = fmaf(w1, pri1[p].y, s1.y);
            s0.z = fmaf(w0, pri0[p].z, s0.z); s1.z = fmaf(w1, pri1[p].z, s1.z);
            s0.w = fmaf(w0, pri0[p].w, s0.w); s1.w = fmaf(w1, pri1[p].w, s1.w);
        }
        if (has4) {                      // wave-uniform tail tile
            float w0 = 1.0f, w1 = 1.0f;
            if (!uni) {
                w0 = __expf(logit0[1024 + rr] - m0);
                w1 = __expf(logit1[1024 + rr] - m1);
            }
            s0.x = fmaf(w0, pri0[4].x, s0.x); s1.x = fmaf(w1, pri1[4].x, s1.x);
            s0.y = fmaf(w0, pri0[4].y, s0.y); s1.y = fmaf(w1, pri1[4].y, s1.y);
            s0.z = fmaf(w0, pri0[4].z, s0.z); s1.z = fmaf(w1, pri1[4].z, s1.z);
            s0.w = fmaf(w0, pri0[4].w, s0.w); s1.w = fmaf(w1, pri1[4].w, s1.w);
        }
        // reduce over 16 rr slots (same og) within each wave
#pragma unroll
        for (int msk = 4; msk <= 32; msk <<= 1) {
            s0.x += __shfl_xor(s0.x, msk, 64); s1.x += __shfl_xor(s1.x, msk, 64);
            s0.y += __shfl_xor(s0.y, msk, 64); s1.y += __shfl_xor(s1.y, msk, 64);
            s0.z += __shfl_xor(s0.z, msk, 64); s1.z += __shfl_xor(s1.z, msk, 64);
            s0.w += __shfl_xor(s0.w, msk, 64); s1.w += __shfl_xor(s1.w, msk, 64);
        }
        __syncthreads();                 // stats reads done; it=0: x reads done
        if (lane < 4) {                  // lane==og here
            ((float4*)red)[wid * 4 + og]      = s0;  // red[wid*16+o]
            ((float4*)(red + 256))[wid * 4 + og] = s1;
        }
        __syncthreads();

        if (t < 2 * OC) {                // t<16: batch0; 16..31: batch1
            const int bsel = t >> 4, o = t & 15;
            float s = 0.f;
#pragma unroll
            for (int w = 0; w < 16; ++w) s += red[bsel * 256 + w * 16 + o];
            s *= uni ? (1.0f / 1152.0f) : (bsel ? invd1 : invd0);
            float sq = s * s;
#pragma unroll
            for (int msk = 1; msk <= 8; msk <<= 1) sq += __shfl_xor(sq, msk, 64);
            float v = s * (sqrtf(sq) / (1.0f + sq));   // squash
            if (it == NITER - 1) out[((size_t)(b0 + bsel) * NC + c) * OC + o] = v;
            else vout[t] = v;
        }
        __syncthreads();

        if (it < NITER - 1) {
            // logit[r] += sum_o pri[r][o]*v[o]
            float4 v0 = ((const float4*)vout)[og];
            float4 v1 = ((const float4*)(vout + OC))[og];
#pragma unroll
            for (int p = 0; p < 4; ++p) {
                const int r = rr + (p << 8);
                float d0 = pri0[p].x * v0.x + pri0[p].y * v0.y +
                           pri0[p].z * v0.z + pri0[p].w * v0.w;
                float d1 = pri1[p].x * v1.x + pri1[p].y * v1.y +
                           pri1[p].z * v1.z + pri1[p].w * v1.w;
                d0 += __shfl_xor(d0, 1, 64); d1 += __shfl_xor(d1, 1, 64);
                d0 += __shfl_xor(d0, 2, 64); d1 += __shfl_xor(d1, 2, 64);
                if (og == 0) {
                    if (it == 0) { logit0[r] = d0; logit1[r] = d1; }
                    else         { logit0[r] += d0; logit1[r] += d1; }
                }
            }
            if (has4) {
                const int r = 1024 + rr;
                float d0 = pri0[4].x * v0.x + pri0[4].y * v0.y +
                           pri0[4].z * v0.z + pri0[4].w * v0.w;
                float d1 = pri1[4].x * v1.x + pri1[4].y * v1.y +
                           pri1[4].z * v1.z + pri1[4].w * v1.w;
                d0 += __shfl_xor(d0, 1, 64); d1 += __shfl_xor(d1, 1, 64);
                d0 += __shfl_xor(d0, 2, 64); d1 += __shfl_xor(d1, 2, 64);
                if (og == 0) {
                    if (it == 0) { logit0[r] = d0; logit1[r] = d1; }
                    else         { logit0[r] += d0; logit1[r] += d1; }
                }
            }
            __syncthreads();
        }
    }
}

extern "C" void kernel_launch(void* const* d_in, const int* in_sizes, int n_in,
                              void* d_out, int out_size, void* d_ws, size_t ws_size,
                              hipStream_t stream) {
    const float* x = (const float*)d_in[0];
    const float* W = (const float*)d_in[1];
    float* out = (float*)d_out;
    caps_route<<<dim3(NC * (256 / MB)), dim3(T), 0, stream>>>(x, W, out);
}

// Round 8
// 137.243 us; speedup vs baseline: 1.1380x; 1.1380x over previous
//
#include <hip/hip_runtime.h>
#include <math.h>

// CapsuleLayer dynamic routing, fused. R8 = R4 minus x-LDS staging.
// Cross-round ledger: per-wave efficiency (dur x occ) best in the clean-
// register 512-thr shape (R5=2200, others 3300-4900); R4<->R5 showed NOT
// L2-BW-bound; allocator pins VGPR<=64 in ALL configs (R2/R3/R6/R7), so
// demand must fit under 64: RPT=9 @ 512 thr = 44 regs (R4-proven, no spill).
// The missing factor is RESIDENT WAVES: x now read from global (L2/L3-hot,
// contiguous 512B/wave/tile) -> LDS 5.2 KB -> 4 blocks/CU = 32 waves = 100%
// theoretical occupancy; 4 independent blocks overlap latency + barriers.
// c-major blocks: 256 consecutive blocks share W[c] (589 KB) in L2.

#define NBATCH 256
#define NC 10
#define NR 1152
#define IC 8
#define OC 16
#define NITER 3
#define T 512
#define RPT 9    // NR / 128 r-values per thread

__device__ __forceinline__ float wave_sum(float v) {
#pragma unroll
    for (int m = 1; m <= 32; m <<= 1) v += __shfl_xor(v, m, 64);
    return v;
}
__device__ __forceinline__ float wave_max(float v) {
#pragma unroll
    for (int m = 1; m <= 32; m <<= 1) v = fmaxf(v, __shfl_xor(v, m, 64));
    return v;
}

__global__ __launch_bounds__(T) void caps_route(
    const float* __restrict__ x,   // [B, NR, IC]
    const float* __restrict__ W,   // [NC, NR, IC, OC]
    float* __restrict__ out)       // [B, NC, OC]
{
    __shared__ float logit[NR];    // collapsed logits (broadcast over OC)
    __shared__ float red[128];     // 8 waves x 16 outputs
    __shared__ float vout[OC];     // current output vector

    const int t    = threadIdx.x;
    const int og   = t & 3;        // o-quad (o = og*4+j)
    const int rr   = t >> 2;       // 0..127
    const int lane = t & 63;
    const int wid  = t >> 6;       // 0..7

    const int c = blockIdx.x >> 8; // c-major: 256 consecutive blocks share W[c]
    const int b = blockIdx.x & 255;

    // ---------------- Phase A: pri[p] = priors[r=rr+128p][o-quad og] -------
    // x read straight from global: per wave per tile the 16 rr-lanes touch
    // x[b, r..r+15] = 512 contiguous bytes (og-redundancy = cache broadcast).
    float4 pri[RPT];
    const float4* __restrict__ xb = (const float4*)(x + (size_t)b * (NR * IC));
    const float4* __restrict__ wb = (const float4*)(W + (size_t)c * (NR * IC * OC));
#pragma unroll
    for (int p = 0; p < RPT; ++p) {
        const int r = rr + (p << 7);
        float4 xa = xb[2 * r];
        float4 xc = xb[2 * r + 1];
        const float4* wp = wb + (size_t)r * 32 + og; // float4 idx (r*8+i)*4+og
        float xv[8] = {xa.x, xa.y, xa.z, xa.w, xc.x, xc.y, xc.z, xc.w};
        float4 acc = make_float4(0.f, 0.f, 0.f, 0.f);
#pragma unroll
        for (int i = 0; i < 8; ++i) {
            float4 w = wp[i * 4];
            acc.x = fmaf(xv[i], w.x, acc.x);
            acc.y = fmaf(xv[i], w.y, acc.y);
            acc.z = fmaf(xv[i], w.z, acc.z);
            acc.w = fmaf(xv[i], w.w, acc.w);
        }
        pri[p] = acc;
    }

    // ---------------- Phase B: 3 routing iterations -------------------------
    for (int it = 0; it < NITER; ++it) {
        const bool uni = (it == 0);  // softmax of zeros = uniform
        float m = 0.f, invd = 0.f;
        if (!uni) {
            float lm = -3.4e38f;
#pragma unroll
            for (int k = 0; k < 3; ++k) {
                int r = t + (k << 9);
                if (r < NR) lm = fmaxf(lm, logit[r]);
            }
            lm = wave_max(lm);
            if (lane == 0) red[wid] = lm;
            __syncthreads();
            m = red[0];
#pragma unroll
            for (int w = 1; w < 8; ++w) m = fmaxf(m, red[w]);
            float ls = 0.f;
#pragma unroll
            for (int k = 0; k < 3; ++k) {
                int r = t + (k << 9);
                if (r < NR) ls += __expf(logit[r] - m);
            }
            ls = wave_sum(ls);
            __syncthreads();             // max reads done before red rewrite
            if (lane == 0) red[wid] = ls;
            __syncthreads();
            float den = red[0];
#pragma unroll
            for (int w = 1; w < 8; ++w) den += red[w];
            invd = 1.f / den;
        }

        // s[o] partial = sum over owned r of probs[r]*pri[r][o]
        float4 s4 = make_float4(0.f, 0.f, 0.f, 0.f);
#pragma unroll
        for (int k = 0; k < RPT; ++k) {
            float wgt = 1.0f;
            if (!uni) wgt = __expf(logit[rr + (k << 7)] - m);
            s4.x = fmaf(wgt, pri[k].x, s4.x);
            s4.y = fmaf(wgt, pri[k].y, s4.y);
            s4.z = fmaf(wgt, pri[k].z, s4.z);
            s4.w = fmaf(wgt, pri[k].w, s4.w);
        }
        // reduce over the 16 rr slots (same og) within each wave
#pragma unroll
        for (int msk = 4; msk <= 32; msk <<= 1) {
            s4.x += __shfl_xor(s4.x, msk, 64);
            s4.y += __shfl_xor(s4.y, msk, 64);
            s4.z += __shfl_xor(s4.z, msk, 64);
            s4.w += __shfl_xor(s4.w, msk, 64);
        }
        __syncthreads();                 // stats/prev-red reads done
        if (lane < 4) ((float4*)red)[wid * 4 + og] = s4; // red[wid*16 + o]
        __syncthreads();

        if (t < OC) {                    // 16 threads of wave 0
            float s = 0.f;
#pragma unroll
            for (int w = 0; w < 8; ++w) s += red[w * 16 + t];
            s *= uni ? (1.0f / 1152.0f) : invd;
            float sq = s * s;
#pragma unroll
            for (int msk = 1; msk <= 8; msk <<= 1) sq += __shfl_xor(sq, msk, 64);
            float v = s * (sqrtf(sq) / (1.0f + sq)); // squash
            if (it == NITER - 1) out[((size_t)b * NC + c) * OC + t] = v;
            else vout[t] = v;
        }
        __syncthreads();

        if (it < NITER - 1) {
            // logit[r] += sum_o pri[r][o]*v[o]
            float4 v4 = ((const float4*)vout)[og];
#pragma unroll
            for (int k = 0; k < RPT; ++k) {
                const int r = rr + (k << 7);
                float d = pri[k].x * v4.x + pri[k].y * v4.y +
                          pri[k].z * v4.z + pri[k].w * v4.w;
                d += __shfl_xor(d, 1, 64);
                d += __shfl_xor(d, 2, 64);
                if (og == 0) {
                    if (it == 0) logit[r] = d;   // logits start at zero
                    else         logit[r] += d;
                }
            }
            __syncthreads();
        }
    }
}

extern "C" void kernel_launch(void* const* d_in, const int* in_sizes, int n_in,
                              void* d_out, int out_size, void* d_ws, size_t ws_size,
                              hipStream_t stream) {
    const float* x = (const float*)d_in[0];
    const float* W = (const float*)d_in[1];
    float* out = (float*)d_out;
    caps_route<<<dim3(NC * NBATCH), dim3(T), 0, stream>>>(x, W, out);
}